// Round 1
// baseline (2998.937 us; speedup 1.0000x reference)
//
#include <hip/hip_runtime.h>

// GAT forward: ft = X @ W (N,128); head-0 attention scores; segment softmax
// over dst; out[dst] += a * ft[src]  (all 4 heads share head-0 attention).
//
// ws layout: ft (N*128 f32) | s_l (N) | s_r (N) | emax (N u32) | denom (N) | ebuf (E)

#define ALPHA 0.2f

// ---------- order-preserving float<->uint encoding for atomicMax ----------
__device__ __forceinline__ unsigned enc_f(float f) {
    unsigned u = __float_as_uint(f);
    return (u & 0x80000000u) ? ~u : (u | 0x80000000u);
}
__device__ __forceinline__ float dec_f(unsigned u) {
    return __uint_as_float((u & 0x80000000u) ? (u ^ 0x80000000u) : ~u);
}

// ---------- zero d_out ----------
__global__ void zero_kernel(float4* __restrict__ p, int n4) {
    int i = blockIdx.x * 256 + threadIdx.x;
    if (i < n4) p[i] = make_float4(0.f, 0.f, 0.f, 0.f);
}

// ---------- GEMM: ft = A(N,128) @ W(128,128) ----------
// block: 256 threads, 32 rows per block. Each thread: 4x4 microtile.
__global__ __launch_bounds__(256) void gemm_kernel(
        const float* __restrict__ A, const float* __restrict__ W,
        float* __restrict__ ft, int N) {
    __shared__ float a_sh[32][128];
    const int tid = threadIdx.x;
    const int block_row = blockIdx.x * 32;

    // stage A tile (32x128 = 1024 float4), 4 float4 per thread, coalesced
    {
        const float4* A4 = (const float4*)(A + (size_t)block_row * 128);
        float4* S4 = (float4*)&a_sh[0][0];
        for (int t = tid; t < 1024; t += 256) {
            int r = t >> 5;                      // row within tile
            float4 v = make_float4(0.f, 0.f, 0.f, 0.f);
            if (block_row + r < N) v = A4[t];
            S4[t] = v;
        }
    }
    __syncthreads();

    const int tm = tid >> 5;   // 0..7  -> rows tm*4 .. tm*4+3
    const int tn = tid & 31;   // 0..31 -> cols tn*4 .. tn*4+3

    float acc[4][4];
    #pragma unroll
    for (int r = 0; r < 4; ++r)
        #pragma unroll
        for (int c = 0; c < 4; ++c) acc[r][c] = 0.f;

    const float4* W4 = (const float4*)W;
    #pragma unroll 4
    for (int k = 0; k < 128; ++k) {
        float4 w = W4[k * 32 + tn];           // coalesced; L2-resident
        #pragma unroll
        for (int r = 0; r < 4; ++r) {
            float av = a_sh[tm * 4 + r][k];   // wave-broadcast, conflict-free
            acc[r][0] += av * w.x;
            acc[r][1] += av * w.y;
            acc[r][2] += av * w.z;
            acc[r][3] += av * w.w;
        }
    }

    #pragma unroll
    for (int r = 0; r < 4; ++r) {
        int row = block_row + tm * 4 + r;
        if (row < N) {
            float4 o = make_float4(acc[r][0], acc[r][1], acc[r][2], acc[r][3]);
            ((float4*)(ft + (size_t)row * 128))[tn] = o;
        }
    }
}

// ---------- per-node: head-0 scores + init emax/denom ----------
__global__ void node_kernel(const float* __restrict__ ft,
                            const float* __restrict__ attn_l,
                            const float* __restrict__ attn_r,
                            float* __restrict__ s_l, float* __restrict__ s_r,
                            unsigned* __restrict__ emax, float* __restrict__ denom,
                            int N) {
    int n = blockIdx.x * 256 + threadIdx.x;
    if (n >= N) return;
    const float4* row = (const float4*)(ft + (size_t)n * 128);  // head 0 = first 32 floats
    const float4* al = (const float4*)attn_l;
    const float4* ar = (const float4*)attn_r;
    float sl = 0.f, sr = 0.f;
    #pragma unroll
    for (int j = 0; j < 8; ++j) {
        float4 v = row[j];
        float4 l = al[j];
        float4 r = ar[j];
        sl += v.x * l.x + v.y * l.y + v.z * l.z + v.w * l.w;
        sr += v.x * r.x + v.y * r.y + v.z * r.z + v.w * r.w;
    }
    s_l[n] = sl;
    s_r[n] = sr;
    emax[n] = 0u;        // == enc of "less than any real float" (max identity)
    denom[n] = 0.f;
}

// ---------- edge pass 1: e = leaky_relu(s_l[src]+s_r[dst]); atomicMax emax ----------
__global__ void edge1_kernel(const int* __restrict__ src, const int* __restrict__ dst,
                             const float* __restrict__ s_l, const float* __restrict__ s_r,
                             float* __restrict__ ebuf, unsigned* __restrict__ emax, int E) {
    int i = blockIdx.x * 256 + threadIdx.x;
    if (i >= E) return;
    int s = src[i], d = dst[i];
    float x = s_l[s] + s_r[d];
    float e = (x > 0.f) ? x : ALPHA * x;
    ebuf[i] = e;
    atomicMax(&emax[d], enc_f(e));
}

// ---------- edge pass 2: ex = exp(e - emax[dst]); atomicAdd denom ----------
__global__ void edge2_kernel(const int* __restrict__ dst,
                             float* __restrict__ ebuf, const unsigned* __restrict__ emax,
                             float* __restrict__ denom, int E) {
    int i = blockIdx.x * 256 + threadIdx.x;
    if (i >= E) return;
    int d = dst[i];
    float ex = __expf(ebuf[i] - dec_f(emax[d]));
    ebuf[i] = ex;
    atomicAdd(&denom[d], ex);
}

// ---------- scatter: out[dst] += (ex/denom[dst]) * ft[src], 128 feats/edge ----------
// 32 threads per edge, float4 per thread.
__global__ __launch_bounds__(256) void scatter_kernel(
        const int* __restrict__ src, const int* __restrict__ dst,
        const float* __restrict__ ft, const float* __restrict__ ebuf,
        const float* __restrict__ denom, float* __restrict__ out, int E) {
    int gid = blockIdx.x * 256 + threadIdx.x;
    int i = gid >> 5;          // edge
    int j = gid & 31;          // float4 index within 128-feature row
    if (i >= E) return;
    int s = src[i], d = dst[i];
    float a = ebuf[i] / denom[d];
    float4 v = ((const float4*)(ft + (size_t)s * 128))[j];
    float* o = out + (size_t)d * 128 + j * 4;
    atomicAdd(o + 0, v.x * a);
    atomicAdd(o + 1, v.y * a);
    atomicAdd(o + 2, v.z * a);
    atomicAdd(o + 3, v.w * a);
}

extern "C" void kernel_launch(void* const* d_in, const int* in_sizes, int n_in,
                              void* d_out, int out_size, void* d_ws, size_t ws_size,
                              hipStream_t stream) {
    const float* inputs = (const float*)d_in[0];
    const int*   src    = (const int*)d_in[1];
    const int*   dst    = (const int*)d_in[2];
    const float* fc_w   = (const float*)d_in[3];
    const float* attn_l = (const float*)d_in[4];
    const float* attn_r = (const float*)d_in[5];
    float* out = (float*)d_out;

    const int N = in_sizes[0] / 128;
    const int E = in_sizes[1];

    char* w = (char*)d_ws;
    float*    ft    = (float*)w;     w += (size_t)N * 128 * sizeof(float);
    float*    s_l   = (float*)w;     w += (size_t)N * sizeof(float);
    float*    s_r   = (float*)w;     w += (size_t)N * sizeof(float);
    unsigned* emax  = (unsigned*)w;  w += (size_t)N * sizeof(unsigned);
    float*    denom = (float*)w;     w += (size_t)N * sizeof(float);
    float*    ebuf  = (float*)w;     w += (size_t)E * sizeof(float);

    // zero the output (it is poisoned 0xAA before every timed call)
    {
        int n4 = (N * 128) / 4;
        zero_kernel<<<(n4 + 255) / 256, 256, 0, stream>>>((float4*)out, n4);
    }

    // ft = inputs @ fc_w
    gemm_kernel<<<(N + 31) / 32, 256, 0, stream>>>(inputs, fc_w, ft, N);

    // per-node scores + init
    node_kernel<<<(N + 255) / 256, 256, 0, stream>>>(ft, attn_l, attn_r,
                                                     s_l, s_r, emax, denom, N);

    // edge passes
    edge1_kernel<<<(E + 255) / 256, 256, 0, stream>>>(src, dst, s_l, s_r, ebuf, emax, E);
    edge2_kernel<<<(E + 255) / 256, 256, 0, stream>>>(dst, ebuf, emax, denom, E);

    // weighted scatter-sum
    {
        long long total = (long long)E * 32;
        int blocks = (int)((total + 255) / 256);
        scatter_kernel<<<blocks, 256, 0, stream>>>(src, dst, ft, ebuf, denom, out, E);
    }
}

// Round 2
// 562.016 us; speedup vs baseline: 5.3360x; 5.3360x over previous
//
#include <hip/hip_runtime.h>

// GAT forward, CSR-based (no output atomics):
//   1. ft = X @ W               (GEMM, 100k x 128 x 128 fp32)
//   2. s_l/s_r per-node scores  (head 0 only)
//   3. CSR build: hist -> 3-kernel exclusive scan -> fill (edge ids by dst)
//   4. aggregate: per dst node (32-lane group): shfl-reduce max & sum of
//      exp(leaky(s_l[src]+s_r[dst])), then acc += a * ft[src], plain store.
//
// ws: ft (N*128 f32) | s_l (N) | s_r (N) | counts (N u32) | offsets (N u32)
//     | partials (1024 u32) | eidx (E u32)

#define ALPHA 0.2f

// ---------- zero u32 array ----------
__global__ void zero_u32_kernel(unsigned* __restrict__ p, int n) {
    int i = blockIdx.x * 256 + threadIdx.x;
    if (i < n) p[i] = 0u;
}

// ---------- GEMM: ft = A(N,128) @ W(128,128) ----------
__global__ __launch_bounds__(256) void gemm_kernel(
        const float* __restrict__ A, const float* __restrict__ W,
        float* __restrict__ ft, int N) {
    __shared__ float a_sh[32][128];
    const int tid = threadIdx.x;
    const int block_row = blockIdx.x * 32;

    {
        const float4* A4 = (const float4*)(A + (size_t)block_row * 128);
        float4* S4 = (float4*)&a_sh[0][0];
        for (int t = tid; t < 1024; t += 256) {
            int r = t >> 5;
            float4 v = make_float4(0.f, 0.f, 0.f, 0.f);
            if (block_row + r < N) v = A4[t];
            S4[t] = v;
        }
    }
    __syncthreads();

    const int tm = tid >> 5;
    const int tn = tid & 31;

    float acc[4][4];
    #pragma unroll
    for (int r = 0; r < 4; ++r)
        #pragma unroll
        for (int c = 0; c < 4; ++c) acc[r][c] = 0.f;

    const float4* W4 = (const float4*)W;
    #pragma unroll 4
    for (int k = 0; k < 128; ++k) {
        float4 w = W4[k * 32 + tn];
        #pragma unroll
        for (int r = 0; r < 4; ++r) {
            float av = a_sh[tm * 4 + r][k];
            acc[r][0] += av * w.x;
            acc[r][1] += av * w.y;
            acc[r][2] += av * w.z;
            acc[r][3] += av * w.w;
        }
    }

    #pragma unroll
    for (int r = 0; r < 4; ++r) {
        int row = block_row + tm * 4 + r;
        if (row < N) {
            float4 o = make_float4(acc[r][0], acc[r][1], acc[r][2], acc[r][3]);
            ((float4*)(ft + (size_t)row * 128))[tn] = o;
        }
    }
}

// ---------- per-node head-0 scores ----------
__global__ void node_kernel(const float* __restrict__ ft,
                            const float* __restrict__ attn_l,
                            const float* __restrict__ attn_r,
                            float* __restrict__ s_l, float* __restrict__ s_r,
                            int N) {
    int n = blockIdx.x * 256 + threadIdx.x;
    if (n >= N) return;
    const float4* row = (const float4*)(ft + (size_t)n * 128);  // head 0
    const float4* al = (const float4*)attn_l;
    const float4* ar = (const float4*)attn_r;
    float sl = 0.f, sr = 0.f;
    #pragma unroll
    for (int j = 0; j < 8; ++j) {
        float4 v = row[j];
        float4 l = al[j];
        float4 r = ar[j];
        sl += v.x * l.x + v.y * l.y + v.z * l.z + v.w * l.w;
        sr += v.x * r.x + v.y * r.y + v.z * r.z + v.w * r.w;
    }
    s_l[n] = sl;
    s_r[n] = sr;
}

// ---------- CSR: histogram of dst ----------
__global__ void hist_kernel(const int* __restrict__ dst, unsigned* __restrict__ counts, int E) {
    int i = blockIdx.x * 256 + threadIdx.x;
    if (i < E) atomicAdd(&counts[dst[i]], 1u);
}

// ---------- CSR: exclusive scan (1024 elems / block) ----------
__global__ __launch_bounds__(256) void scan1_kernel(const unsigned* __restrict__ counts,
                                                    unsigned* __restrict__ offsets,
                                                    unsigned* __restrict__ partials, int N) {
    __shared__ unsigned sh[256];
    const int tid = threadIdx.x;
    const int base = blockIdx.x * 1024 + tid * 4;
    unsigned v[4];
    unsigned s = 0;
    #pragma unroll
    for (int k = 0; k < 4; ++k) {
        int idx = base + k;
        v[k] = (idx < N) ? counts[idx] : 0u;
        s += v[k];
    }
    sh[tid] = s;
    __syncthreads();
    for (int off = 1; off < 256; off <<= 1) {
        unsigned t = (tid >= off) ? sh[tid - off] : 0u;
        __syncthreads();
        sh[tid] += t;
        __syncthreads();
    }
    if (tid == 255) partials[blockIdx.x] = sh[255];
    unsigned run = (tid == 0) ? 0u : sh[tid - 1];
    #pragma unroll
    for (int k = 0; k < 4; ++k) {
        int idx = base + k;
        if (idx < N) offsets[idx] = run;
        run += v[k];
    }
}

__global__ __launch_bounds__(256) void scan2_kernel(unsigned* __restrict__ partials, int NB) {
    __shared__ unsigned sh[256];
    const int tid = threadIdx.x;
    unsigned v[4];
    unsigned s = 0;
    #pragma unroll
    for (int k = 0; k < 4; ++k) {
        int idx = tid * 4 + k;
        v[k] = (idx < NB) ? partials[idx] : 0u;
        s += v[k];
    }
    sh[tid] = s;
    __syncthreads();
    for (int off = 1; off < 256; off <<= 1) {
        unsigned t = (tid >= off) ? sh[tid - off] : 0u;
        __syncthreads();
        sh[tid] += t;
        __syncthreads();
    }
    unsigned run = (tid == 0) ? 0u : sh[tid - 1];
    #pragma unroll
    for (int k = 0; k < 4; ++k) {
        int idx = tid * 4 + k;
        if (idx < NB) partials[idx] = run;
        run += v[k];
    }
}

__global__ void scan3_kernel(unsigned* __restrict__ offsets,
                             const unsigned* __restrict__ partials, int N) {
    int i = blockIdx.x * 256 + threadIdx.x;
    if (i < N) offsets[i] += partials[i >> 10];
}

// ---------- CSR: fill edge ids (shifts offsets[d] from start to end) ----------
__global__ void fill_kernel(const int* __restrict__ dst, unsigned* __restrict__ offsets,
                            unsigned* __restrict__ eidx, int E) {
    int i = blockIdx.x * 256 + threadIdx.x;
    if (i >= E) return;
    unsigned pos = atomicAdd(&offsets[dst[i]], 1u);
    eidx[pos] = (unsigned)i;
}

// ---------- fused softmax + weighted gather-sum, one 32-lane group per node ----------
// After fill: segment d spans [ (d==0?0:offsets[d-1]), offsets[d] ).
__global__ __launch_bounds__(256) void aggregate_kernel(
        const int* __restrict__ src, const unsigned* __restrict__ eidx,
        const unsigned* __restrict__ offsets,
        const float* __restrict__ s_l, const float* __restrict__ s_r,
        const float* __restrict__ ft, float* __restrict__ out, int N) {
    int gid = blockIdx.x * 256 + threadIdx.x;
    int d = gid >> 5;
    int lane = gid & 31;
    if (d >= N) return;

    unsigned start = (d == 0) ? 0u : offsets[d - 1];
    unsigned end = offsets[d];
    float rdst = s_r[d];

    // phase A: segment max (lanes strided over edges, shfl-reduce)
    float m = -1e30f;
    for (unsigned e = start + lane; e < end; e += 32) {
        int i = (int)eidx[e];
        float x = s_l[src[i]] + rdst;
        float ev = (x > 0.f) ? x : ALPHA * x;
        m = fmaxf(m, ev);
    }
    #pragma unroll
    for (int off = 16; off > 0; off >>= 1) m = fmaxf(m, __shfl_xor(m, off, 32));

    // phase A2: segment sum of exp
    float sum = 0.f;
    for (unsigned e = start + lane; e < end; e += 32) {
        int i = (int)eidx[e];
        float x = s_l[src[i]] + rdst;
        float ev = (x > 0.f) ? x : ALPHA * x;
        sum += __expf(ev - m);
    }
    #pragma unroll
    for (int off = 16; off > 0; off >>= 1) sum += __shfl_xor(sum, off, 32);
    float rden = (end > start) ? 1.f / sum : 0.f;

    // phase B: out[d] = sum_e a_e * ft[src_e]  (all 32 lanes per edge, float4/lane)
    float4 acc = make_float4(0.f, 0.f, 0.f, 0.f);
    for (unsigned e = start; e < end; ++e) {
        int i = (int)eidx[e];
        int s = src[i];
        float x = s_l[s] + rdst;
        float ev = (x > 0.f) ? x : ALPHA * x;
        float a = __expf(ev - m) * rden;
        float4 v = ((const float4*)ft)[(size_t)s * 32 + lane];
        acc.x += a * v.x;
        acc.y += a * v.y;
        acc.z += a * v.z;
        acc.w += a * v.w;
    }
    ((float4*)out)[(size_t)d * 32 + lane] = acc;
}

extern "C" void kernel_launch(void* const* d_in, const int* in_sizes, int n_in,
                              void* d_out, int out_size, void* d_ws, size_t ws_size,
                              hipStream_t stream) {
    const float* inputs = (const float*)d_in[0];
    const int*   src    = (const int*)d_in[1];
    const int*   dst    = (const int*)d_in[2];
    const float* fc_w   = (const float*)d_in[3];
    const float* attn_l = (const float*)d_in[4];
    const float* attn_r = (const float*)d_in[5];
    float* out = (float*)d_out;

    const int N = in_sizes[0] / 128;
    const int E = in_sizes[1];
    const int NB = (N + 1023) / 1024;   // scan blocks (must be <= 1024)

    char* w = (char*)d_ws;
    float*    ft       = (float*)w;     w += (size_t)N * 128 * sizeof(float);
    float*    s_l      = (float*)w;     w += (size_t)N * sizeof(float);
    float*    s_r      = (float*)w;     w += (size_t)N * sizeof(float);
    unsigned* counts   = (unsigned*)w;  w += (size_t)N * sizeof(unsigned);
    unsigned* offsets  = (unsigned*)w;  w += (size_t)N * sizeof(unsigned);
    unsigned* partials = (unsigned*)w;  w += 1024 * sizeof(unsigned);
    unsigned* eidx     = (unsigned*)w;  w += (size_t)E * sizeof(unsigned);

    // ft = inputs @ fc_w
    gemm_kernel<<<(N + 31) / 32, 256, 0, stream>>>(inputs, fc_w, ft, N);

    // per-node scores
    node_kernel<<<(N + 255) / 256, 256, 0, stream>>>(ft, attn_l, attn_r, s_l, s_r, N);

    // CSR build
    zero_u32_kernel<<<(N + 255) / 256, 256, 0, stream>>>(counts, N);
    hist_kernel<<<(E + 255) / 256, 256, 0, stream>>>(dst, counts, E);
    scan1_kernel<<<NB, 256, 0, stream>>>(counts, offsets, partials, N);
    scan2_kernel<<<1, 256, 0, stream>>>(partials, NB);
    scan3_kernel<<<(N + 255) / 256, 256, 0, stream>>>(offsets, partials, N);
    fill_kernel<<<(E + 255) / 256, 256, 0, stream>>>(dst, offsets, eidx, E);

    // fused softmax + aggregation (writes every node, incl. zero-degree -> 0)
    {
        long long total = (long long)N * 32;
        int blocks = (int)((total + 255) / 256);
        aggregate_kernel<<<blocks, 256, 0, stream>>>(src, eidx, offsets,
                                                     s_l, s_r, ft, out, N);
    }
}

// Round 3
// 418.040 us; speedup vs baseline: 7.1738x; 1.3444x over previous
//
#include <hip/hip_runtime.h>

// GAT forward, CSR + bf16-gather version:
//   1. gemm_kernel: ft_bf16 = X @ W (bf16 store), fused s_l/s_r head-0 scores
//   2. CSR build: zero -> hist -> 3-kernel scan -> fill (writes dst-sorted
//      edata[pos] = {src, leaky_score} as uint2; no later indirection)
//   3. aggregate: per dst node (32 lanes): shfl max + sum of exp over
//      sequential edata, then acc += a * ft_bf16[src], plain f32 store.
//
// ws: ftb (N*128 bf16) | s_l (N f32) | s_r (N f32) | counts (N u32)
//     | offsets (N u32) | partials (1024 u32) | edata (E uint2)

#define ALPHA 0.2f

__device__ __forceinline__ unsigned short f2bf(float f) {
    unsigned u = __float_as_uint(f);
    unsigned r = (u + 0x7FFFu + ((u >> 16) & 1u)) >> 16;   // RNE
    return (unsigned short)r;
}
__device__ __forceinline__ float bf2f(unsigned short h) {
    return __uint_as_float(((unsigned)h) << 16);
}

// ---------- zero u32 array ----------
__global__ void zero_u32_kernel(unsigned* __restrict__ p, int n) {
    int i = blockIdx.x * 256 + threadIdx.x;
    if (i < n) p[i] = 0u;
}

// ---------- GEMM: ftb = A(N,128) @ W(128,128), bf16 out + fused scores ----------
// 256 threads, 32 rows/block, 4x4 microtile. W staged through LDS in 64-k chunks.
__global__ __launch_bounds__(256) void gemm_kernel(
        const float* __restrict__ A, const float* __restrict__ W,
        const float* __restrict__ attn_l, const float* __restrict__ attn_r,
        unsigned short* __restrict__ ftb,
        float* __restrict__ s_l, float* __restrict__ s_r, int N) {
    __shared__ float a_sh[32][128];          // 16 KB
    __shared__ float w_sh[64 * 128];         // 32 KB (one 64-k chunk of W)
    const int tid = threadIdx.x;
    const int block_row = blockIdx.x * 32;
    const int tm = tid >> 5;                 // 0..7
    const int tn = tid & 31;                 // 0..31

    // stage A tile (32x128 = 1024 float4)
    {
        const float4* A4 = (const float4*)(A + (size_t)block_row * 128);
        float4* S4 = (float4*)&a_sh[0][0];
        for (int t = tid; t < 1024; t += 256) {
            int r = t >> 5;
            float4 v = make_float4(0.f, 0.f, 0.f, 0.f);
            if (block_row + r < N) v = A4[t];
            S4[t] = v;
        }
    }

    float acc[4][4];
    #pragma unroll
    for (int r = 0; r < 4; ++r)
        #pragma unroll
        for (int c = 0; c < 4; ++c) acc[r][c] = 0.f;

    const float4* W4 = (const float4*)W;
    float4* w_sh4 = (float4*)w_sh;

    for (int ko = 0; ko < 128; ko += 64) {
        __syncthreads();                     // protect w_sh reuse
        // stage 64x128 chunk of W (2048 float4)
        for (int j = tid; j < 2048; j += 256) w_sh4[j] = W4[ko * 32 + j];
        __syncthreads();

        #pragma unroll 4
        for (int kb = 0; kb < 64; kb += 4) {
            float4 wr[4];
            #pragma unroll
            for (int kk = 0; kk < 4; ++kk) wr[kk] = w_sh4[(kb + kk) * 32 + tn];
            float4 ar[4];
            #pragma unroll
            for (int r = 0; r < 4; ++r)
                ar[r] = *(const float4*)&a_sh[tm * 4 + r][ko + kb];
            #pragma unroll
            for (int r = 0; r < 4; ++r) {
                const float av[4] = {ar[r].x, ar[r].y, ar[r].z, ar[r].w};
                #pragma unroll
                for (int kk = 0; kk < 4; ++kk) {
                    acc[r][0] += av[kk] * wr[kk].x;
                    acc[r][1] += av[kk] * wr[kk].y;
                    acc[r][2] += av[kk] * wr[kk].z;
                    acc[r][3] += av[kk] * wr[kk].w;
                }
            }
        }
    }

    // ---- store bf16 ft ----
    #pragma unroll
    for (int r = 0; r < 4; ++r) {
        int row = block_row + tm * 4 + r;
        if (row < N) {
            ushort4 q;
            q.x = f2bf(acc[r][0]); q.y = f2bf(acc[r][1]);
            q.z = f2bf(acc[r][2]); q.w = f2bf(acc[r][3]);
            *(ushort4*)(ftb + (size_t)row * 128 + tn * 4) = q;
        }
    }

    // ---- fused head-0 scores: cols 0..31 live in threads tn<8 ----
    float alv[4] = {0.f, 0.f, 0.f, 0.f}, arv[4] = {0.f, 0.f, 0.f, 0.f};
    if (tn < 8) {
        #pragma unroll
        for (int c = 0; c < 4; ++c) { alv[c] = attn_l[tn * 4 + c]; arv[c] = attn_r[tn * 4 + c]; }
    }
    #pragma unroll
    for (int r = 0; r < 4; ++r) {
        float pl = acc[r][0] * alv[0] + acc[r][1] * alv[1] + acc[r][2] * alv[2] + acc[r][3] * alv[3];
        float pr = acc[r][0] * arv[0] + acc[r][1] * arv[1] + acc[r][2] * arv[2] + acc[r][3] * arv[3];
        #pragma unroll
        for (int mask = 4; mask > 0; mask >>= 1) {
            pl += __shfl_xor(pl, mask);
            pr += __shfl_xor(pr, mask);
        }
        if (tn == 0) {
            int row = block_row + tm * 4 + r;
            if (row < N) { s_l[row] = pl; s_r[row] = pr; }
        }
    }
}

// ---------- CSR: histogram of dst ----------
__global__ void hist_kernel(const int* __restrict__ dst, unsigned* __restrict__ counts, int E) {
    int i = blockIdx.x * 256 + threadIdx.x;
    if (i < E) atomicAdd(&counts[dst[i]], 1u);
}

// ---------- CSR: exclusive scan (1024 elems / block) ----------
__global__ __launch_bounds__(256) void scan1_kernel(const unsigned* __restrict__ counts,
                                                    unsigned* __restrict__ offsets,
                                                    unsigned* __restrict__ partials, int N) {
    __shared__ unsigned sh[256];
    const int tid = threadIdx.x;
    const int base = blockIdx.x * 1024 + tid * 4;
    unsigned v[4];
    unsigned s = 0;
    #pragma unroll
    for (int k = 0; k < 4; ++k) {
        int idx = base + k;
        v[k] = (idx < N) ? counts[idx] : 0u;
        s += v[k];
    }
    sh[tid] = s;
    __syncthreads();
    for (int off = 1; off < 256; off <<= 1) {
        unsigned t = (tid >= off) ? sh[tid - off] : 0u;
        __syncthreads();
        sh[tid] += t;
        __syncthreads();
    }
    if (tid == 255) partials[blockIdx.x] = sh[255];
    unsigned run = (tid == 0) ? 0u : sh[tid - 1];
    #pragma unroll
    for (int k = 0; k < 4; ++k) {
        int idx = base + k;
        if (idx < N) offsets[idx] = run;
        run += v[k];
    }
}

__global__ __launch_bounds__(256) void scan2_kernel(unsigned* __restrict__ partials, int NB) {
    __shared__ unsigned sh[256];
    const int tid = threadIdx.x;
    unsigned v[4];
    unsigned s = 0;
    #pragma unroll
    for (int k = 0; k < 4; ++k) {
        int idx = tid * 4 + k;
        v[k] = (idx < NB) ? partials[idx] : 0u;
        s += v[k];
    }
    sh[tid] = s;
    __syncthreads();
    for (int off = 1; off < 256; off <<= 1) {
        unsigned t = (tid >= off) ? sh[tid - off] : 0u;
        __syncthreads();
        sh[tid] += t;
        __syncthreads();
    }
    unsigned run = (tid == 0) ? 0u : sh[tid - 1];
    #pragma unroll
    for (int k = 0; k < 4; ++k) {
        int idx = tid * 4 + k;
        if (idx < NB) partials[idx] = run;
        run += v[k];
    }
}

__global__ void scan3_kernel(unsigned* __restrict__ offsets,
                             const unsigned* __restrict__ partials, int N) {
    int i = blockIdx.x * 256 + threadIdx.x;
    if (i < N) offsets[i] += partials[i >> 10];
}

// ---------- CSR fill: dst-sorted {src, leaky_score} records ----------
__global__ void fill_kernel(const int* __restrict__ src, const int* __restrict__ dst,
                            const float* __restrict__ s_l, const float* __restrict__ s_r,
                            unsigned* __restrict__ offsets, uint2* __restrict__ edata, int E) {
    int i = blockIdx.x * 256 + threadIdx.x;
    if (i >= E) return;
    int s = src[i], d = dst[i];
    float x = s_l[s] + s_r[d];
    float e = (x > 0.f) ? x : ALPHA * x;
    unsigned pos = atomicAdd(&offsets[d], 1u);
    edata[pos] = make_uint2((unsigned)s, __float_as_uint(e));
}

// ---------- fused softmax + weighted gather-sum, 32 lanes / node ----------
// After fill: segment d = [ (d==0?0:offsets[d-1]), offsets[d] ).
__global__ __launch_bounds__(256) void aggregate_kernel(
        const uint2* __restrict__ edata, const unsigned* __restrict__ offsets,
        const unsigned short* __restrict__ ftb, float* __restrict__ out, int N) {
    int gid = blockIdx.x * 256 + threadIdx.x;
    int d = gid >> 5;
    int lane = gid & 31;
    if (d >= N) return;

    unsigned start = (d == 0) ? 0u : offsets[d - 1];
    unsigned end = offsets[d];

    // segment max (coalesced sequential reads)
    float m = -1e30f;
    for (unsigned e = start + lane; e < end; e += 32)
        m = fmaxf(m, __uint_as_float(edata[e].y));
    #pragma unroll
    for (int off = 16; off > 0; off >>= 1) m = fmaxf(m, __shfl_xor(m, off, 32));

    // segment sum of exp
    float sum = 0.f;
    for (unsigned e = start + lane; e < end; e += 32)
        sum += __expf(__uint_as_float(edata[e].y) - m);
    #pragma unroll
    for (int off = 16; off > 0; off >>= 1) sum += __shfl_xor(sum, off, 32);
    float rden = (end > start) ? 1.f / sum : 0.f;

    // weighted gather-accumulate over bf16 ft
    float4 acc = make_float4(0.f, 0.f, 0.f, 0.f);
    for (unsigned e = start; e < end; ++e) {
        uint2 ed = edata[e];
        float a = __expf(__uint_as_float(ed.y) - m) * rden;
        ushort4 q = *(const ushort4*)(ftb + (size_t)ed.x * 128 + lane * 4);
        acc.x += a * bf2f(q.x);
        acc.y += a * bf2f(q.y);
        acc.z += a * bf2f(q.z);
        acc.w += a * bf2f(q.w);
    }
    ((float4*)out)[(size_t)d * 32 + lane] = acc;
}

extern "C" void kernel_launch(void* const* d_in, const int* in_sizes, int n_in,
                              void* d_out, int out_size, void* d_ws, size_t ws_size,
                              hipStream_t stream) {
    const float* inputs = (const float*)d_in[0];
    const int*   src    = (const int*)d_in[1];
    const int*   dst    = (const int*)d_in[2];
    const float* fc_w   = (const float*)d_in[3];
    const float* attn_l = (const float*)d_in[4];
    const float* attn_r = (const float*)d_in[5];
    float* out = (float*)d_out;

    const int N = in_sizes[0] / 128;
    const int E = in_sizes[1];
    const int NB = (N + 1023) / 1024;   // scan blocks (<= 1024)

    char* w = (char*)d_ws;
    unsigned short* ftb = (unsigned short*)w;  w += (size_t)N * 128 * sizeof(unsigned short);
    float*    s_l      = (float*)w;     w += (size_t)N * sizeof(float);
    float*    s_r      = (float*)w;     w += (size_t)N * sizeof(float);
    unsigned* counts   = (unsigned*)w;  w += (size_t)N * sizeof(unsigned);
    unsigned* offsets  = (unsigned*)w;  w += (size_t)N * sizeof(unsigned);
    unsigned* partials = (unsigned*)w;  w += 1024 * sizeof(unsigned);
    uint2*    edata    = (uint2*)w;     w += (size_t)E * sizeof(uint2);

    // ft (bf16) + fused scores
    gemm_kernel<<<(N + 31) / 32, 256, 0, stream>>>(inputs, fc_w, attn_l, attn_r,
                                                   ftb, s_l, s_r, N);

    // CSR build
    zero_u32_kernel<<<(N + 255) / 256, 256, 0, stream>>>(counts, N);
    hist_kernel<<<(E + 255) / 256, 256, 0, stream>>>(dst, counts, E);
    scan1_kernel<<<NB, 256, 0, stream>>>(counts, offsets, partials, N);
    scan2_kernel<<<1, 256, 0, stream>>>(partials, NB);
    scan3_kernel<<<(N + 255) / 256, 256, 0, stream>>>(offsets, partials, N);
    fill_kernel<<<(E + 255) / 256, 256, 0, stream>>>(src, dst, s_l, s_r, offsets, edata, E);

    // fused softmax + aggregation
    {
        long long total = (long long)N * 32;
        int blocks = (int)((total + 255) / 256);
        aggregate_kernel<<<blocks, 256, 0, stream>>>(edata, offsets, ftb, out, N);
    }
}

// Round 4
// 358.987 us; speedup vs baseline: 8.3539x; 1.1645x over previous
//
#include <hip/hip_runtime.h>

// GAT forward, MFMA-GEMM + CSR + bf16-gather:
//   0. prep: zero counts; build Wswz = W^T as bf16, 16B-chunk XOR-swizzled
//   1. gemm (MFMA 16x16x32 bf16): ftb = bf16(A) @ bf16(W), fused s_l/s_r
//      head-0 scores, C transposed through LDS for coalesced stores
//   2. CSR: hist -> scan1 -> scan2 (partials applied at use sites)
//   3. fill: dst-sorted edata[pos] = {src, leaky_score}
//   4. aggregate: one 64-lane wave per dst node; shfl max/sum; gather phase
//      runs 2 edges across half-waves x unroll 2 (4 loads in flight)
//
// ws: ftb (N*128 bf16) | s_l (N) | s_r (N) | counts (N u32) | offsets (N u32)
//     | partials (1024 u32) | Wswz (2048 x 16B) | edata (E uint2)

#define ALPHA 0.2f

typedef __attribute__((ext_vector_type(8))) short bf16x8;
typedef __attribute__((ext_vector_type(8))) unsigned short u16x8;
typedef __attribute__((ext_vector_type(4))) float f32x4;

__device__ __forceinline__ unsigned short f2bf(float f) {
    unsigned u = __float_as_uint(f);
    unsigned r = (u + 0x7FFFu + ((u >> 16) & 1u)) >> 16;   // RNE
    return (unsigned short)r;
}
__device__ __forceinline__ float bf2f(unsigned short h) {
    return __uint_as_float(((unsigned)h) << 16);
}

// ---------- prep: zero counts + build swizzled bf16 W^T ----------
// Wswz chunk (n, c) holds Wt[n][c*8 .. c*8+7] = W[k][n], stored at n*16 + (c ^ (n&7)).
__global__ __launch_bounds__(256) void prep_kernel(const float* __restrict__ W,
                                                   unsigned* __restrict__ counts,
                                                   u16x8* __restrict__ Wswz, int N) {
    int gt = blockIdx.x * 256 + threadIdx.x;
    if (gt < 2048) {
        int n = gt >> 4, c = gt & 15;
        u16x8 v;
        #pragma unroll
        for (int j = 0; j < 8; ++j) v[j] = f2bf(W[(c * 8 + j) * 128 + n]);
        Wswz[n * 16 + (c ^ (n & 7))] = v;
    }
    for (int i = gt; i < N; i += 256 * 256) counts[i] = 0u;
}

// ---------- MFMA GEMM: ftb = bf16(A) @ bf16(W) + fused head-0 scores ----------
// 256 threads = 4 waves; 64 rows/block; wave w: rows 16w..16w+15, all 128 cols.
// A-frag layout: A[m=lane&15][k=quad*8+j]; B-frag: B[k=quad*8+j][n=lane&15];
// C-frag: col=lane&15, row=quad*4+reg.
__global__ __launch_bounds__(256) void gemm_kernel(
        const float* __restrict__ A, const u16x8* __restrict__ Wswz,
        const float* __restrict__ attn_l, const float* __restrict__ attn_r,
        unsigned short* __restrict__ ftb,
        float* __restrict__ s_l, float* __restrict__ s_r, int N) {
    __shared__ u16x8 A_lds[1024];   // 64 rows x 16 chunks, XOR-swizzled (16 KB)
    __shared__ u16x8 W_lds[2048];   // 128 n x 16 chunks, pre-swizzled  (32 KB)
    const int tid = threadIdx.x;
    const int block_row = blockIdx.x * 64;

    // stage W (linear copy; swizzle already applied by prep)
    for (int i = tid; i < 2048; i += 256) W_lds[i] = Wswz[i];

    // stage A: fp32 -> bf16, chunk (m,c) -> m*16 + (c ^ (m&7))
    for (int l = tid; l < 1024; l += 256) {
        int m = l >> 4, c = l & 15;
        int row = block_row + m;
        float4 v0 = make_float4(0.f, 0.f, 0.f, 0.f), v1 = v0;
        if (row < N) {
            const float4* p = (const float4*)(A + (size_t)row * 128 + c * 8);
            v0 = p[0]; v1 = p[1];
        }
        u16x8 u;
        u[0] = f2bf(v0.x); u[1] = f2bf(v0.y); u[2] = f2bf(v0.z); u[3] = f2bf(v0.w);
        u[4] = f2bf(v1.x); u[5] = f2bf(v1.y); u[6] = f2bf(v1.z); u[7] = f2bf(v1.w);
        A_lds[m * 16 + (c ^ (m & 7))] = u;
    }
    __syncthreads();

    const int wv = tid >> 6;
    const int lane = tid & 63;
    const int lm = lane & 15;
    const int quad = lane >> 4;

    f32x4 acc[8];
    #pragma unroll
    for (int t = 0; t < 8; ++t) acc[t] = (f32x4)(0.f);

    const int am = wv * 16 + lm;
    #pragma unroll
    for (int ks = 0; ks < 4; ++ks) {
        int c = ks * 4 + quad;                       // k chunk = (ks*32 + quad*8)/8
        bf16x8 af = *(const bf16x8*)&A_lds[am * 16 + (c ^ (am & 7))];
        #pragma unroll
        for (int t = 0; t < 8; ++t) {
            int n = t * 16 + lm;
            bf16x8 bf = *(const bf16x8*)&W_lds[n * 16 + (c ^ (n & 7))];
            acc[t] = __builtin_amdgcn_mfma_f32_16x16x32_bf16(af, bf, acc[t], 0, 0, 0);
        }
    }

    // fused head-0 scores (cols 0..31 live in frags 0,1)
    {
        float al0 = attn_l[lm], al1 = attn_l[16 + lm];
        float ar0 = attn_r[lm], ar1 = attn_r[16 + lm];
        #pragma unroll
        for (int r = 0; r < 4; ++r) {
            float pl = acc[0][r] * al0 + acc[1][r] * al1;
            float pr = acc[0][r] * ar0 + acc[1][r] * ar1;
            #pragma unroll
            for (int mask = 1; mask < 16; mask <<= 1) {
                pl += __shfl_xor(pl, mask, 64);
                pr += __shfl_xor(pr, mask, 64);
            }
            if (lm == 0) {
                int row = block_row + wv * 16 + quad * 4 + r;
                if (row < N) { s_l[row] = pl; s_r[row] = pr; }
            }
        }
    }

    // transpose C through LDS (reuse A_lds region; each wave owns its 16 rows)
    unsigned short* C_lds = (unsigned short*)A_lds;
    #pragma unroll
    for (int t = 0; t < 8; ++t) {
        #pragma unroll
        for (int r = 0; r < 4; ++r) {
            int mrow = wv * 16 + quad * 4 + r;
            C_lds[mrow * 128 + t * 16 + lm] = f2bf(acc[t][r]);
        }
    }
    __syncthreads();

    // coalesced bf16 store
    for (int l = tid; l < 1024; l += 256) {
        int m = l >> 4, c = l & 15;
        int row = block_row + m;
        if (row < N)
            *(u16x8*)(ftb + (size_t)row * 128 + c * 8) = *(const u16x8*)&C_lds[m * 128 + c * 8];
    }
}

// ---------- CSR: histogram of dst ----------
__global__ void hist_kernel(const int* __restrict__ dst, unsigned* __restrict__ counts, int E) {
    int i = blockIdx.x * 256 + threadIdx.x;
    if (i < E) atomicAdd(&counts[dst[i]], 1u);
}

// ---------- CSR: block-local exclusive scan (1024/block) + block totals ----------
__global__ __launch_bounds__(256) void scan1_kernel(const unsigned* __restrict__ counts,
                                                    unsigned* __restrict__ offsets,
                                                    unsigned* __restrict__ partials, int N) {
    __shared__ unsigned sh[256];
    const int tid = threadIdx.x;
    const int base = blockIdx.x * 1024 + tid * 4;
    unsigned v[4];
    unsigned s = 0;
    #pragma unroll
    for (int k = 0; k < 4; ++k) {
        int idx = base + k;
        v[k] = (idx < N) ? counts[idx] : 0u;
        s += v[k];
    }
    sh[tid] = s;
    __syncthreads();
    for (int off = 1; off < 256; off <<= 1) {
        unsigned t = (tid >= off) ? sh[tid - off] : 0u;
        __syncthreads();
        sh[tid] += t;
        __syncthreads();
    }
    if (tid == 255) partials[blockIdx.x] = sh[255];
    unsigned run = (tid == 0) ? 0u : sh[tid - 1];
    #pragma unroll
    for (int k = 0; k < 4; ++k) {
        int idx = base + k;
        if (idx < N) offsets[idx] = run;
        run += v[k];
    }
}

// exclusive scan of block totals (NB <= 1024)
__global__ __launch_bounds__(256) void scan2_kernel(unsigned* __restrict__ partials, int NB) {
    __shared__ unsigned sh[256];
    const int tid = threadIdx.x;
    unsigned v[4];
    unsigned s = 0;
    #pragma unroll
    for (int k = 0; k < 4; ++k) {
        int idx = tid * 4 + k;
        v[k] = (idx < NB) ? partials[idx] : 0u;
        s += v[k];
    }
    sh[tid] = s;
    __syncthreads();
    for (int off = 1; off < 256; off <<= 1) {
        unsigned t = (tid >= off) ? sh[tid - off] : 0u;
        __syncthreads();
        sh[tid] += t;
        __syncthreads();
    }
    unsigned run = (tid == 0) ? 0u : sh[tid - 1];
    #pragma unroll
    for (int k = 0; k < 4; ++k) {
        int idx = tid * 4 + k;
        if (idx < NB) partials[idx] = run;
        run += v[k];
    }
}

// ---------- fill: dst-sorted {src, leaky_score}; global pos = local + partials ----------
__global__ void fill_kernel(const int* __restrict__ src, const int* __restrict__ dst,
                            const float* __restrict__ s_l, const float* __restrict__ s_r,
                            unsigned* __restrict__ offsets, const unsigned* __restrict__ partials,
                            uint2* __restrict__ edata, int E) {
    int i = blockIdx.x * 256 + threadIdx.x;
    if (i >= E) return;
    int s = src[i], d = dst[i];
    float x = s_l[s] + s_r[d];
    float e = (x > 0.f) ? x : ALPHA * x;
    unsigned pos = atomicAdd(&offsets[d], 1u) + partials[d >> 10];
    edata[pos] = make_uint2((unsigned)s, __float_as_uint(e));
}

// ---------- fused softmax + weighted gather-sum, one 64-lane wave per node ----------
// Segment d = [off(d-1), off(d)) with off(x) = offsets[x] + partials[x>>10]
// (offsets[x] = local_excl + count after fill).
__global__ __launch_bounds__(256) void aggregate_kernel(
        const uint2* __restrict__ edata, const unsigned* __restrict__ offsets,
        const unsigned* __restrict__ partials,
        const unsigned short* __restrict__ ftb, float* __restrict__ out, int N) {
    int wv = threadIdx.x >> 6;
    int lane = threadIdx.x & 63;
    int d = blockIdx.x * 4 + wv;
    if (d >= N) return;

    unsigned start = (d == 0) ? 0u : (offsets[d - 1] + partials[(d - 1) >> 10]);
    unsigned end = offsets[d] + partials[d >> 10];

    // segment max over 64 lanes
    float m = -1e30f;
    for (unsigned e = start + lane; e < end; e += 64)
        m = fmaxf(m, __uint_as_float(edata[e].y));
    #pragma unroll
    for (int mask = 1; mask < 64; mask <<= 1) m = fmaxf(m, __shfl_xor(m, mask, 64));

    // segment sum of exp
    float sum = 0.f;
    for (unsigned e = start + lane; e < end; e += 64)
        sum += __expf(__uint_as_float(edata[e].y) - m);
    #pragma unroll
    for (int mask = 1; mask < 64; mask <<= 1) sum += __shfl_xor(sum, mask, 64);
    float rden = (end > start) ? 1.f / sum : 0.f;

    // gather: half-waves take alternating edges, unroll x2 -> 4 loads in flight
    int eh = lane >> 5, j = lane & 31;
    float4 acc = make_float4(0.f, 0.f, 0.f, 0.f);
    unsigned e = start + eh;
    for (; e + 2 < end; e += 4) {
        uint2 ed0 = edata[e];
        uint2 ed1 = edata[e + 2];
        ushort4 q0 = *(const ushort4*)(ftb + (size_t)ed0.x * 128 + j * 4);
        ushort4 q1 = *(const ushort4*)(ftb + (size_t)ed1.x * 128 + j * 4);
        float a0 = __expf(__uint_as_float(ed0.y) - m) * rden;
        float a1 = __expf(__uint_as_float(ed1.y) - m) * rden;
        acc.x += a0 * bf2f(q0.x) + a1 * bf2f(q1.x);
        acc.y += a0 * bf2f(q0.y) + a1 * bf2f(q1.y);
        acc.z += a0 * bf2f(q0.z) + a1 * bf2f(q1.z);
        acc.w += a0 * bf2f(q0.w) + a1 * bf2f(q1.w);
    }
    for (; e < end; e += 2) {
        uint2 ed = edata[e];
        ushort4 q = *(const ushort4*)(ftb + (size_t)ed.x * 128 + j * 4);
        float a = __expf(__uint_as_float(ed.y) - m) * rden;
        acc.x += a * bf2f(q.x);
        acc.y += a * bf2f(q.y);
        acc.z += a * bf2f(q.z);
        acc.w += a * bf2f(q.w);
    }

    // combine the two half-wave partials, lanes 0..31 store
    acc.x += __shfl_xor(acc.x, 32, 64);
    acc.y += __shfl_xor(acc.y, 32, 64);
    acc.z += __shfl_xor(acc.z, 32, 64);
    acc.w += __shfl_xor(acc.w, 32, 64);
    if (eh == 0)
        ((float4*)out)[(size_t)d * 32 + j] = acc;
}

static inline size_t align256(size_t x) { return (x + 255) & ~(size_t)255; }

extern "C" void kernel_launch(void* const* d_in, const int* in_sizes, int n_in,
                              void* d_out, int out_size, void* d_ws, size_t ws_size,
                              hipStream_t stream) {
    const float* inputs = (const float*)d_in[0];
    const int*   src    = (const int*)d_in[1];
    const int*   dst    = (const int*)d_in[2];
    const float* fc_w   = (const float*)d_in[3];
    const float* attn_l = (const float*)d_in[4];
    const float* attn_r = (const float*)d_in[5];
    float* out = (float*)d_out;

    const int N = in_sizes[0] / 128;
    const int E = in_sizes[1];
    const int NB = (N + 1023) / 1024;   // scan blocks (<= 1024)

    char* w = (char*)d_ws;
    unsigned short* ftb = (unsigned short*)w;  w += align256((size_t)N * 128 * 2);
    float*    s_l      = (float*)w;     w += align256((size_t)N * 4);
    float*    s_r      = (float*)w;     w += align256((size_t)N * 4);
    unsigned* counts   = (unsigned*)w;  w += align256((size_t)N * 4);
    unsigned* offsets  = (unsigned*)w;  w += align256((size_t)N * 4);
    unsigned* partials = (unsigned*)w;  w += align256(1024 * 4);
    u16x8*    Wswz     = (u16x8*)w;     w += align256(2048 * 16);
    uint2*    edata    = (uint2*)w;     w += align256((size_t)E * 8);

    prep_kernel<<<256, 256, 0, stream>>>(fc_w, counts, Wswz, N);
    gemm_kernel<<<(N + 63) / 64, 256, 0, stream>>>(inputs, Wswz, attn_l, attn_r,
                                                   ftb, s_l, s_r, N);
    hist_kernel<<<(E + 255) / 256, 256, 0, stream>>>(dst, counts, E);
    scan1_kernel<<<NB, 256, 0, stream>>>(counts, offsets, partials, N);
    scan2_kernel<<<1, 256, 0, stream>>>(partials, NB);
    fill_kernel<<<(E + 255) / 256, 256, 0, stream>>>(src, dst, s_l, s_r,
                                                     offsets, partials, edata, E);
    aggregate_kernel<<<(N + 3) / 4, 256, 0, stream>>>(edata, offsets, partials,
                                                      ftb, out, N);
}

// Round 5
// 276.180 us; speedup vs baseline: 10.8586x; 1.2998x over previous
//
#include <hip/hip_runtime.h>

// GAT forward — MFMA GEMM + two-level bucket CSR + weighted gather:
//   0. prep: build Wswz (bf16 W^T, 16B-chunk XOR swizzle)
//   1. gemm (MFMA 16x16x32 bf16): ftb, fused head-0 scores s_l/s_r
//   2. bhist: per-(block,bucket) histogram, bucket = dst>>8 (LDS atomics only)
//   3. scan1/scan2/scan3: exact exclusive scan of bh[bucket][block]
//   4. bscatter: e=leaky(s_l[src]+s_r[dst]); staged[pos]={src|dlow<<20, e},
//      pos exact from scan -> coalesced ~64B runs
//   5. bsort: block per bucket; LDS counting sort by dst; per-dst softmax in
//      LDS; writes edata={src, a_final} in-place (coalesced) + offsets[d]
//   6. aggregate: wave per dst; pure gather: acc += a * ft[src]
//
// ws: ftb | s_l | s_r | bh (M u32) | S (M u32) | partials (1024) |
//     offsets (N u32) | Wswz (2048x16B) | staged/edata (E uint2)

#define ALPHA 0.2f
#define NBLK 512           // partition blocks
#define BBITS 8
#define BSIZE 256          // dsts per bucket
#define CAP 5120           // bsort LDS record capacity (mean 4096, +16 sigma)

typedef __attribute__((ext_vector_type(8))) short bf16x8;
typedef __attribute__((ext_vector_type(8))) unsigned short u16x8;
typedef __attribute__((ext_vector_type(4))) float f32x4;

__device__ __forceinline__ unsigned short f2bf(float f) {
    unsigned u = __float_as_uint(f);
    unsigned r = (u + 0x7FFFu + ((u >> 16) & 1u)) >> 16;   // RNE
    return (unsigned short)r;
}
__device__ __forceinline__ float bf2f(unsigned short h) {
    return __uint_as_float(((unsigned)h) << 16);
}

// ---------- prep: build swizzled bf16 W^T ----------
__global__ __launch_bounds__(256) void prep_kernel(const float* __restrict__ W,
                                                   u16x8* __restrict__ Wswz) {
    int gt = blockIdx.x * 256 + threadIdx.x;
    if (gt < 2048) {
        int n = gt >> 4, c = gt & 15;
        u16x8 v;
        #pragma unroll
        for (int j = 0; j < 8; ++j) v[j] = f2bf(W[(c * 8 + j) * 128 + n]);
        Wswz[n * 16 + (c ^ (n & 7))] = v;
    }
}

// ---------- MFMA GEMM: ftb = bf16(A) @ bf16(W) + fused head-0 scores ----------
__global__ __launch_bounds__(256) void gemm_kernel(
        const float* __restrict__ A, const u16x8* __restrict__ Wswz,
        const float* __restrict__ attn_l, const float* __restrict__ attn_r,
        unsigned short* __restrict__ ftb,
        float* __restrict__ s_l, float* __restrict__ s_r, int N) {
    __shared__ u16x8 A_lds[1024];   // 64 rows x 16 chunks, XOR-swizzled
    __shared__ u16x8 W_lds[2048];   // 128 n x 16 chunks, pre-swizzled
    const int tid = threadIdx.x;
    const int block_row = blockIdx.x * 64;

    for (int i = tid; i < 2048; i += 256) W_lds[i] = Wswz[i];

    for (int l = tid; l < 1024; l += 256) {
        int m = l >> 4, c = l & 15;
        int row = block_row + m;
        float4 v0 = make_float4(0.f, 0.f, 0.f, 0.f), v1 = v0;
        if (row < N) {
            const float4* p = (const float4*)(A + (size_t)row * 128 + c * 8);
            v0 = p[0]; v1 = p[1];
        }
        u16x8 u;
        u[0] = f2bf(v0.x); u[1] = f2bf(v0.y); u[2] = f2bf(v0.z); u[3] = f2bf(v0.w);
        u[4] = f2bf(v1.x); u[5] = f2bf(v1.y); u[6] = f2bf(v1.z); u[7] = f2bf(v1.w);
        A_lds[m * 16 + (c ^ (m & 7))] = u;
    }
    __syncthreads();

    const int wv = tid >> 6;
    const int lane = tid & 63;
    const int lm = lane & 15;
    const int quad = lane >> 4;

    f32x4 acc[8];
    #pragma unroll
    for (int t = 0; t < 8; ++t) acc[t] = (f32x4)(0.f);

    const int am = wv * 16 + lm;
    #pragma unroll
    for (int ks = 0; ks < 4; ++ks) {
        int c = ks * 4 + quad;
        bf16x8 af = *(const bf16x8*)&A_lds[am * 16 + (c ^ (am & 7))];
        #pragma unroll
        for (int t = 0; t < 8; ++t) {
            int n = t * 16 + lm;
            bf16x8 bf = *(const bf16x8*)&W_lds[n * 16 + (c ^ (n & 7))];
            acc[t] = __builtin_amdgcn_mfma_f32_16x16x32_bf16(af, bf, acc[t], 0, 0, 0);
        }
    }

    // fused head-0 scores (cols 0..31 live in frags 0,1)
    {
        float al0 = attn_l[lm], al1 = attn_l[16 + lm];
        float ar0 = attn_r[lm], ar1 = attn_r[16 + lm];
        #pragma unroll
        for (int r = 0; r < 4; ++r) {
            float pl = acc[0][r] * al0 + acc[1][r] * al1;
            float pr = acc[0][r] * ar0 + acc[1][r] * ar1;
            #pragma unroll
            for (int mask = 1; mask < 16; mask <<= 1) {
                pl += __shfl_xor(pl, mask, 64);
                pr += __shfl_xor(pr, mask, 64);
            }
            if (lm == 0) {
                int row = block_row + wv * 16 + quad * 4 + r;
                if (row < N) { s_l[row] = pl; s_r[row] = pr; }
            }
        }
    }

    // transpose C through LDS, then coalesced bf16 store
    unsigned short* C_lds = (unsigned short*)A_lds;
    #pragma unroll
    for (int t = 0; t < 8; ++t) {
        #pragma unroll
        for (int r = 0; r < 4; ++r) {
            int mrow = wv * 16 + quad * 4 + r;
            C_lds[mrow * 128 + t * 16 + lm] = f2bf(acc[t][r]);
        }
    }
    __syncthreads();
    for (int l = tid; l < 1024; l += 256) {
        int m = l >> 4, c = l & 15;
        int row = block_row + m;
        if (row < N)
            *(u16x8*)(ftb + (size_t)row * 128 + c * 8) = *(const u16x8*)&C_lds[m * 128 + c * 8];
    }
}

// ---------- bhist: per-(block,bucket) histogram ----------
__global__ __launch_bounds__(256) void bhist_kernel(const int* __restrict__ dst,
                                                    unsigned* __restrict__ bh,
                                                    int E, int nbucket, int slice) {
    __shared__ unsigned cnt[512];
    for (int i = threadIdx.x; i < nbucket; i += 256) cnt[i] = 0u;
    __syncthreads();
    const int b = blockIdx.x;
    int s0 = b * slice, s1 = min(s0 + slice, E);
    for (int i = s0 + threadIdx.x; i < s1; i += 256)
        atomicAdd(&cnt[((unsigned)dst[i]) >> BBITS], 1u);
    __syncthreads();
    for (int k = threadIdx.x; k < nbucket; k += 256)
        bh[(size_t)k * NBLK + b] = cnt[k];
}

// ---------- scan1: block-local exclusive scan (1024/block) + totals ----------
__global__ __launch_bounds__(256) void scan1_kernel(const unsigned* __restrict__ counts,
                                                    unsigned* __restrict__ S,
                                                    unsigned* __restrict__ partials, int M) {
    __shared__ unsigned sh[256];
    const int tid = threadIdx.x;
    const int base = blockIdx.x * 1024 + tid * 4;
    unsigned v[4];
    unsigned s = 0;
    #pragma unroll
    for (int k = 0; k < 4; ++k) {
        int idx = base + k;
        v[k] = (idx < M) ? counts[idx] : 0u;
        s += v[k];
    }
    sh[tid] = s;
    __syncthreads();
    for (int off = 1; off < 256; off <<= 1) {
        unsigned t = (tid >= off) ? sh[tid - off] : 0u;
        __syncthreads();
        sh[tid] += t;
        __syncthreads();
    }
    if (tid == 255) partials[blockIdx.x] = sh[255];
    unsigned run = (tid == 0) ? 0u : sh[tid - 1];
    #pragma unroll
    for (int k = 0; k < 4; ++k) {
        int idx = base + k;
        if (idx < M) S[idx] = run;
        run += v[k];
    }
}

// ---------- scan2: exclusive scan of block totals (NB <= 1024) ----------
__global__ __launch_bounds__(256) void scan2_kernel(unsigned* __restrict__ partials, int NB) {
    __shared__ unsigned sh[256];
    const int tid = threadIdx.x;
    unsigned v[4];
    unsigned s = 0;
    #pragma unroll
    for (int k = 0; k < 4; ++k) {
        int idx = tid * 4 + k;
        v[k] = (idx < NB) ? partials[idx] : 0u;
        s += v[k];
    }
    sh[tid] = s;
    __syncthreads();
    for (int off = 1; off < 256; off <<= 1) {
        unsigned t = (tid >= off) ? sh[tid - off] : 0u;
        __syncthreads();
        sh[tid] += t;
        __syncthreads();
    }
    unsigned run = (tid == 0) ? 0u : sh[tid - 1];
    #pragma unroll
    for (int k = 0; k < 4; ++k) {
        int idx = tid * 4 + k;
        if (idx < NB) partials[idx] = run;
        run += v[k];
    }
}

// ---------- scan3: apply partials in-place ----------
__global__ void scan3_kernel(unsigned* __restrict__ S,
                             const unsigned* __restrict__ partials, int M) {
    int i = blockIdx.x * 256 + threadIdx.x;
    if (i < M) S[i] += partials[i >> 10];
}

// ---------- bscatter: staged[pos] = {src | dlow<<20, leaky_score} ----------
__global__ __launch_bounds__(256) void bscatter_kernel(
        const int* __restrict__ src, const int* __restrict__ dst,
        const float* __restrict__ s_l, const float* __restrict__ s_r,
        const unsigned* __restrict__ S, uint2* __restrict__ staged,
        int E, int nbucket, int slice) {
    __shared__ unsigned cur[512];
    for (int i = threadIdx.x; i < nbucket; i += 256) cur[i] = 0u;
    __syncthreads();
    const int b = blockIdx.x;
    int s0 = b * slice, s1 = min(s0 + slice, E);
    for (int i = s0 + threadIdx.x; i < s1; i += 256) {
        int s = src[i], d = dst[i];
        unsigned k = ((unsigned)d) >> BBITS;
        float x = s_l[s] + s_r[d];
        float e = (x > 0.f) ? x : ALPHA * x;
        unsigned pos = S[(size_t)k * NBLK + b] + atomicAdd(&cur[k], 1u);
        staged[pos] = make_uint2((unsigned)s | (((unsigned)d & (BSIZE - 1)) << 20),
                                 __float_as_uint(e));
    }
}

// ---------- bsort: per-bucket counting sort + softmax; in-place rewrite ----------
__global__ __launch_bounds__(256) void bsort_kernel(
        uint2* __restrict__ staged, const unsigned* __restrict__ S,
        unsigned* __restrict__ offsets, int N, int E, int nbucket) {
    __shared__ uint2 rec[CAP];
    __shared__ unsigned cnt[BSIZE], incl[BSIZE], cur[BSIZE];
    const int k = blockIdx.x;
    const int t = threadIdx.x;
    unsigned gstart = S[(size_t)k * NBLK];
    unsigned gend = (k + 1 == nbucket) ? (unsigned)E : S[(size_t)(k + 1) * NBLK];
    int n = (int)(gend - gstart);
    if (n > CAP) n = CAP;   // statistically impossible; avoid corruption

    cnt[t] = 0u;
    __syncthreads();
    for (int i = t; i < n; i += 256)
        atomicAdd(&cnt[staged[gstart + i].x >> 20], 1u);
    __syncthreads();
    // inclusive scan of cnt
    incl[t] = cnt[t];
    __syncthreads();
    for (int off = 1; off < 256; off <<= 1) {
        unsigned u = (t >= off) ? incl[t - off] : 0u;
        __syncthreads();
        incl[t] += u;
        __syncthreads();
    }
    cur[t] = 0u;
    __syncthreads();
    // place into sorted LDS order
    for (int i = t; i < n; i += 256) {
        uint2 r = staged[gstart + i];
        unsigned dl = r.x >> 20;
        unsigned p = incl[dl] - cnt[dl] + atomicAdd(&cur[dl], 1u);
        rec[p] = r;
    }
    __syncthreads();
    // per-dst softmax -> final weights, write offsets (end)
    int d = k * BSIZE + t;
    if (d < N) {
        int b0 = (int)(incl[t] - cnt[t]);
        int c = (int)cnt[t];
        float m = -1e30f;
        for (int j = 0; j < c; ++j) m = fmaxf(m, __uint_as_float(rec[b0 + j].y));
        float sum = 0.f;
        for (int j = 0; j < c; ++j) sum += __expf(__uint_as_float(rec[b0 + j].y) - m);
        float rden = (c > 0) ? 1.f / sum : 0.f;
        for (int j = 0; j < c; ++j) {
            float a = __expf(__uint_as_float(rec[b0 + j].y) - m) * rden;
            rec[b0 + j].y = __float_as_uint(a);
        }
        offsets[d] = gstart + incl[t];
    }
    __syncthreads();
    // coalesced in-place write-back {src, a}
    for (int i = t; i < n; i += 256) {
        uint2 r = rec[i];
        staged[gstart + i] = make_uint2(r.x & 0xFFFFFu, r.y);
    }
}

// ---------- aggregate: pure weighted gather, one 64-lane wave per node ----------
__global__ __launch_bounds__(256) void aggregate_kernel(
        const uint2* __restrict__ edata, const unsigned* __restrict__ offsets,
        const unsigned short* __restrict__ ftb, float* __restrict__ out, int N) {
    int wv = threadIdx.x >> 6;
    int lane = threadIdx.x & 63;
    int d = blockIdx.x * 4 + wv;
    if (d >= N) return;

    unsigned start = (d == 0) ? 0u : offsets[d - 1];
    unsigned end = offsets[d];

    int eh = lane >> 5, j = lane & 31;
    float4 acc = make_float4(0.f, 0.f, 0.f, 0.f);
    unsigned e = start + eh;
    for (; e + 2 < end; e += 4) {
        uint2 ed0 = edata[e];
        uint2 ed1 = edata[e + 2];
        ushort4 q0 = *(const ushort4*)(ftb + (size_t)ed0.x * 128 + j * 4);
        ushort4 q1 = *(const ushort4*)(ftb + (size_t)ed1.x * 128 + j * 4);
        float a0 = __uint_as_float(ed0.y);
        float a1 = __uint_as_float(ed1.y);
        acc.x += a0 * bf2f(q0.x) + a1 * bf2f(q1.x);
        acc.y += a0 * bf2f(q0.y) + a1 * bf2f(q1.y);
        acc.z += a0 * bf2f(q0.z) + a1 * bf2f(q1.z);
        acc.w += a0 * bf2f(q0.w) + a1 * bf2f(q1.w);
    }
    for (; e < end; e += 2) {
        uint2 ed = edata[e];
        ushort4 q = *(const ushort4*)(ftb + (size_t)ed.x * 128 + j * 4);
        float a = __uint_as_float(ed.y);
        acc.x += a * bf2f(q.x);
        acc.y += a * bf2f(q.y);
        acc.z += a * bf2f(q.z);
        acc.w += a * bf2f(q.w);
    }

    acc.x += __shfl_xor(acc.x, 32, 64);
    acc.y += __shfl_xor(acc.y, 32, 64);
    acc.z += __shfl_xor(acc.z, 32, 64);
    acc.w += __shfl_xor(acc.w, 32, 64);
    if (eh == 0)
        ((float4*)out)[(size_t)d * 32 + j] = acc;
}

static inline size_t align256(size_t x) { return (x + 255) & ~(size_t)255; }

extern "C" void kernel_launch(void* const* d_in, const int* in_sizes, int n_in,
                              void* d_out, int out_size, void* d_ws, size_t ws_size,
                              hipStream_t stream) {
    const float* inputs = (const float*)d_in[0];
    const int*   src    = (const int*)d_in[1];
    const int*   dst    = (const int*)d_in[2];
    const float* fc_w   = (const float*)d_in[3];
    const float* attn_l = (const float*)d_in[4];
    const float* attn_r = (const float*)d_in[5];
    float* out = (float*)d_out;

    const int N = in_sizes[0] / 128;
    const int E = in_sizes[1];
    const int nbucket = (N + BSIZE - 1) / BSIZE;       // 391
    const int M = nbucket * NBLK;                      // 200192
    const int NB1 = (M + 1023) / 1024;                 // scan1 blocks (<=1024)
    const int slice = (E + NBLK - 1) / NBLK;           // edges per partition block

    char* w = (char*)d_ws;
    unsigned short* ftb = (unsigned short*)w;  w += align256((size_t)N * 128 * 2);
    float*    s_l      = (float*)w;     w += align256((size_t)N * 4);
    float*    s_r      = (float*)w;     w += align256((size_t)N * 4);
    unsigned* bh       = (unsigned*)w;  w += align256((size_t)M * 4);
    unsigned* S        = (unsigned*)w;  w += align256((size_t)M * 4);
    unsigned* partials = (unsigned*)w;  w += align256(1024 * 4);
    unsigned* offsets  = (unsigned*)w;  w += align256((size_t)N * 4);
    u16x8*    Wswz     = (u16x8*)w;     w += align256(2048 * 16);
    uint2*    staged   = (uint2*)w;     w += align256((size_t)E * 8);  // also final edata

    prep_kernel<<<8, 256, 0, stream>>>(fc_w, Wswz);
    gemm_kernel<<<(N + 63) / 64, 256, 0, stream>>>(inputs, Wswz, attn_l, attn_r,
                                                   ftb, s_l, s_r, N);
    bhist_kernel<<<NBLK, 256, 0, stream>>>(dst, bh, E, nbucket, slice);
    scan1_kernel<<<NB1, 256, 0, stream>>>(bh, S, partials, M);
    scan2_kernel<<<1, 256, 0, stream>>>(partials, NB1);
    scan3_kernel<<<(M + 255) / 256, 256, 0, stream>>>(S, partials, M);
    bscatter_kernel<<<NBLK, 256, 0, stream>>>(src, dst, s_l, s_r, S, staged,
                                              E, nbucket, slice);
    bsort_kernel<<<nbucket, 256, 0, stream>>>(staged, S, offsets, N, E, nbucket);
    aggregate_kernel<<<(N + 3) / 4, 256, 0, stream>>>(staged, offsets, ftb, out, N);
}

// Round 6
// 255.772 us; speedup vs baseline: 11.7250x; 1.0798x over previous
//
#include <hip/hip_runtime.h>

// GAT forward — MFMA GEMM + two-level bucket CSR + weighted gather:
//   0. prep: build Wswz (bf16 W^T, 16B-chunk XOR swizzle)
//   1. front (fused): blocks [0,GB): MFMA gemm -> ftb + fused head-0 scores;
//      blocks [GB,GB+NBLK): bhist per-(block,bucket) histogram (bucket=dst>>8)
//   2. scan1/scan2: exclusive scan of bh[bucket][block] (partials applied at use)
//   3. bscatter: staged[pos]={src|dlow<<20, leaky_score}, exact pos -> coalesced
//   4. bsort: block/bucket LDS counting sort + per-dst softmax; edata={src,a}
//   5. aggregate: wave/dst, 16 lanes/edge x 4 slots x stride-8 (8 gathers in flight)
//
// ws: ftb | s_l | s_r | bh (M u32) | S (M u32) | partials (1024) |
//     offsets (N u32) | Wswz (2048x16B) | staged/edata (E uint2)

#define ALPHA 0.2f
#define NBLK 512           // partition blocks
#define BBITS 8
#define BSIZE 256          // dsts per bucket
#define CAP 5120           // bsort LDS record capacity (mean 4096, +16 sigma)

typedef __attribute__((ext_vector_type(8))) short bf16x8;
typedef __attribute__((ext_vector_type(8))) unsigned short u16x8;
typedef __attribute__((ext_vector_type(4))) float f32x4;

__device__ __forceinline__ unsigned short f2bf(float f) {
    unsigned u = __float_as_uint(f);
    unsigned r = (u + 0x7FFFu + ((u >> 16) & 1u)) >> 16;   // RNE
    return (unsigned short)r;
}

// ---------- prep: build swizzled bf16 W^T ----------
__global__ __launch_bounds__(256) void prep_kernel(const float* __restrict__ W,
                                                   u16x8* __restrict__ Wswz) {
    int gt = blockIdx.x * 256 + threadIdx.x;
    if (gt < 2048) {
        int n = gt >> 4, c = gt & 15;
        u16x8 v;
        #pragma unroll
        for (int j = 0; j < 8; ++j) v[j] = f2bf(W[(c * 8 + j) * 128 + n]);
        Wswz[n * 16 + (c ^ (n & 7))] = v;
    }
}

// ---------- front: fused MFMA GEMM + bhist ----------
__global__ __launch_bounds__(256) void front_kernel(
        const float* __restrict__ A, const u16x8* __restrict__ Wswz,
        const float* __restrict__ attn_l, const float* __restrict__ attn_r,
        unsigned short* __restrict__ ftb,
        float* __restrict__ s_l, float* __restrict__ s_r, int N, int GB,
        const int* __restrict__ dst, unsigned* __restrict__ bh,
        int E, int nbucket, int slice) {
    __shared__ char smem[49152];
    const int tid = threadIdx.x;

    if (blockIdx.x >= (unsigned)GB) {
        // ---------------- bhist body ----------------
        unsigned* cnt = (unsigned*)smem;
        for (int i = tid; i < nbucket; i += 256) cnt[i] = 0u;
        __syncthreads();
        const int b = blockIdx.x - GB;
        int s0 = b * slice, s1 = min(s0 + slice, E);
        for (int i = s0 + tid; i < s1; i += 256)
            atomicAdd(&cnt[((unsigned)dst[i]) >> BBITS], 1u);
        __syncthreads();
        for (int k = tid; k < nbucket; k += 256)
            bh[(size_t)k * NBLK + b] = cnt[k];
        return;
    }

    // ---------------- gemm body ----------------
    u16x8* A_lds = (u16x8*)smem;                 // 64 rows x 16 chunks (16 KB)
    u16x8* W_lds = (u16x8*)(smem + 16384);       // 128 n x 16 chunks (32 KB)
    const int block_row = blockIdx.x * 64;

    for (int i = tid; i < 2048; i += 256) W_lds[i] = Wswz[i];

    for (int l = tid; l < 1024; l += 256) {
        int m = l >> 4, c = l & 15;
        int row = block_row + m;
        float4 v0 = make_float4(0.f, 0.f, 0.f, 0.f), v1 = v0;
        if (row < N) {
            const float4* p = (const float4*)(A + (size_t)row * 128 + c * 8);
            v0 = p[0]; v1 = p[1];
        }
        u16x8 u;
        u[0] = f2bf(v0.x); u[1] = f2bf(v0.y); u[2] = f2bf(v0.z); u[3] = f2bf(v0.w);
        u[4] = f2bf(v1.x); u[5] = f2bf(v1.y); u[6] = f2bf(v1.z); u[7] = f2bf(v1.w);
        A_lds[m * 16 + (c ^ (m & 7))] = u;
    }
    __syncthreads();

    const int wv = tid >> 6;
    const int lane = tid & 63;
    const int lm = lane & 15;
    const int quad = lane >> 4;

    f32x4 acc[8];
    #pragma unroll
    for (int t = 0; t < 8; ++t) acc[t] = (f32x4)(0.f);

    const int am = wv * 16 + lm;
    #pragma unroll
    for (int ks = 0; ks < 4; ++ks) {
        int c = ks * 4 + quad;
        bf16x8 af = *(const bf16x8*)&A_lds[am * 16 + (c ^ (am & 7))];
        #pragma unroll
        for (int t = 0; t < 8; ++t) {
            int n = t * 16 + lm;
            bf16x8 bf = *(const bf16x8*)&W_lds[n * 16 + (c ^ (n & 7))];
            acc[t] = __builtin_amdgcn_mfma_f32_16x16x32_bf16(af, bf, acc[t], 0, 0, 0);
        }
    }

    // fused head-0 scores (cols 0..31 live in frags 0,1)
    {
        float al0 = attn_l[lm], al1 = attn_l[16 + lm];
        float ar0 = attn_r[lm], ar1 = attn_r[16 + lm];
        #pragma unroll
        for (int r = 0; r < 4; ++r) {
            float pl = acc[0][r] * al0 + acc[1][r] * al1;
            float pr = acc[0][r] * ar0 + acc[1][r] * ar1;
            #pragma unroll
            for (int mask = 1; mask < 16; mask <<= 1) {
                pl += __shfl_xor(pl, mask, 64);
                pr += __shfl_xor(pr, mask, 64);
            }
            if (lm == 0) {
                int row = block_row + wv * 16 + quad * 4 + r;
                if (row < N) { s_l[row] = pl; s_r[row] = pr; }
            }
        }
    }

    // transpose C through LDS, then coalesced bf16 store
    unsigned short* C_lds = (unsigned short*)A_lds;
    #pragma unroll
    for (int t = 0; t < 8; ++t) {
        #pragma unroll
        for (int r = 0; r < 4; ++r) {
            int mrow = wv * 16 + quad * 4 + r;
            C_lds[mrow * 128 + t * 16 + lm] = f2bf(acc[t][r]);
        }
    }
    __syncthreads();
    for (int l = tid; l < 1024; l += 256) {
        int m = l >> 4, c = l & 15;
        int row = block_row + m;
        if (row < N)
            *(u16x8*)(ftb + (size_t)row * 128 + c * 8) = *(const u16x8*)&C_lds[m * 128 + c * 8];
    }
}

// ---------- scan1: block-local exclusive scan (1024/block) + totals ----------
__global__ __launch_bounds__(256) void scan1_kernel(const unsigned* __restrict__ counts,
                                                    unsigned* __restrict__ S,
                                                    unsigned* __restrict__ partials, int M) {
    __shared__ unsigned sh[256];
    const int tid = threadIdx.x;
    const int base = blockIdx.x * 1024 + tid * 4;
    unsigned v[4];
    unsigned s = 0;
    #pragma unroll
    for (int k = 0; k < 4; ++k) {
        int idx = base + k;
        v[k] = (idx < M) ? counts[idx] : 0u;
        s += v[k];
    }
    sh[tid] = s;
    __syncthreads();
    for (int off = 1; off < 256; off <<= 1) {
        unsigned t = (tid >= off) ? sh[tid - off] : 0u;
        __syncthreads();
        sh[tid] += t;
        __syncthreads();
    }
    if (tid == 255) partials[blockIdx.x] = sh[255];
    unsigned run = (tid == 0) ? 0u : sh[tid - 1];
    #pragma unroll
    for (int k = 0; k < 4; ++k) {
        int idx = base + k;
        if (idx < M) S[idx] = run;
        run += v[k];
    }
}

// ---------- scan2: exclusive scan of block totals (NB <= 1024) ----------
__global__ __launch_bounds__(256) void scan2_kernel(unsigned* __restrict__ partials, int NB) {
    __shared__ unsigned sh[256];
    const int tid = threadIdx.x;
    unsigned v[4];
    unsigned s = 0;
    #pragma unroll
    for (int k = 0; k < 4; ++k) {
        int idx = tid * 4 + k;
        v[k] = (idx < NB) ? partials[idx] : 0u;
        s += v[k];
    }
    sh[tid] = s;
    __syncthreads();
    for (int off = 1; off < 256; off <<= 1) {
        unsigned t = (tid >= off) ? sh[tid - off] : 0u;
        __syncthreads();
        sh[tid] += t;
        __syncthreads();
    }
    unsigned run = (tid == 0) ? 0u : sh[tid - 1];
    #pragma unroll
    for (int k = 0; k < 4; ++k) {
        int idx = tid * 4 + k;
        if (idx < NB) partials[idx] = run;
        run += v[k];
    }
}

// ---------- bscatter: staged[pos] = {src | dlow<<20, leaky_score} ----------
// partials folded in here (scan3 eliminated): base preloaded to LDS per block.
__global__ __launch_bounds__(256) void bscatter_kernel(
        const int* __restrict__ src, const int* __restrict__ dst,
        const float* __restrict__ s_l, const float* __restrict__ s_r,
        const unsigned* __restrict__ S, const unsigned* __restrict__ partials,
        uint2* __restrict__ staged, int E, int nbucket, int slice) {
    __shared__ unsigned basel[512];
    __shared__ unsigned cur[512];
    const int b = blockIdx.x;
    for (int k = threadIdx.x; k < nbucket; k += 256) {
        unsigned idx = (unsigned)k * NBLK + b;
        basel[k] = S[idx] + partials[idx >> 10];
        cur[k] = 0u;
    }
    __syncthreads();
    int s0 = b * slice, s1 = min(s0 + slice, E);
    for (int i = s0 + threadIdx.x; i < s1; i += 256) {
        int s = src[i], d = dst[i];
        unsigned k = ((unsigned)d) >> BBITS;
        float x = s_l[s] + s_r[d];
        float e = (x > 0.f) ? x : ALPHA * x;
        unsigned pos = basel[k] + atomicAdd(&cur[k], 1u);
        staged[pos] = make_uint2((unsigned)s | (((unsigned)d & (BSIZE - 1)) << 20),
                                 __float_as_uint(e));
    }
}

// ---------- bsort: per-bucket counting sort + softmax; in-place rewrite ----------
__global__ __launch_bounds__(256) void bsort_kernel(
        uint2* __restrict__ staged, const unsigned* __restrict__ S,
        const unsigned* __restrict__ partials,
        unsigned* __restrict__ offsets, int N, int E, int nbucket) {
    __shared__ uint2 rec[CAP];
    __shared__ unsigned cnt[BSIZE], incl[BSIZE], cur[BSIZE];
    const int k = blockIdx.x;
    const int t = threadIdx.x;
    unsigned idx0 = (unsigned)k * NBLK;
    unsigned gstart = S[idx0] + partials[idx0 >> 10];
    unsigned gend = (k + 1 == nbucket) ? (unsigned)E
                                       : (S[idx0 + NBLK] + partials[(idx0 + NBLK) >> 10]);
    int n = (int)(gend - gstart);
    if (n > CAP) n = CAP;   // statistically impossible; avoid corruption

    cnt[t] = 0u;
    __syncthreads();
    for (int i = t; i < n; i += 256)
        atomicAdd(&cnt[staged[gstart + i].x >> 20], 1u);
    __syncthreads();
    incl[t] = cnt[t];
    __syncthreads();
    for (int off = 1; off < 256; off <<= 1) {
        unsigned u = (t >= off) ? incl[t - off] : 0u;
        __syncthreads();
        incl[t] += u;
        __syncthreads();
    }
    cur[t] = 0u;
    __syncthreads();
    for (int i = t; i < n; i += 256) {
        uint2 r = staged[gstart + i];
        unsigned dl = r.x >> 20;
        unsigned p = incl[dl] - cnt[dl] + atomicAdd(&cur[dl], 1u);
        rec[p] = r;
    }
    __syncthreads();
    int d = k * BSIZE + t;
    if (d < N) {
        int b0 = (int)(incl[t] - cnt[t]);
        int c = (int)cnt[t];
        float m = -1e30f;
        for (int j = 0; j < c; ++j) m = fmaxf(m, __uint_as_float(rec[b0 + j].y));
        float sum = 0.f;
        for (int j = 0; j < c; ++j) sum += __expf(__uint_as_float(rec[b0 + j].y) - m);
        float rden = (c > 0) ? 1.f / sum : 0.f;
        for (int j = 0; j < c; ++j) {
            float a = __expf(__uint_as_float(rec[b0 + j].y) - m) * rden;
            rec[b0 + j].y = __float_as_uint(a);
        }
        offsets[d] = gstart + incl[t];
    }
    __syncthreads();
    for (int i = t; i < n; i += 256) {
        uint2 r = rec[i];
        staged[gstart + i] = make_uint2(r.x & 0xFFFFFu, r.y);
    }
}

// ---------- aggregate: weighted gather, wave per node ----------
// 16 lanes/edge (ushort8=16B each), 4 edge slots, stride 8 -> 8 gathers in flight.
__global__ __launch_bounds__(256) void aggregate_kernel(
        const uint2* __restrict__ edata, const unsigned* __restrict__ offsets,
        const unsigned short* __restrict__ ftb, float* __restrict__ out, int N) {
    int wv = threadIdx.x >> 6;
    int lane = threadIdx.x & 63;
    int d = blockIdx.x * 4 + wv;
    if (d >= N) return;
    int eh = lane >> 4;          // edge slot 0..3
    int j  = lane & 15;          // feat group: feats j*8 .. j*8+7

    unsigned start = (d == 0) ? 0u : offsets[d - 1];
    unsigned end = offsets[d];

    float acc[8] = {0.f, 0.f, 0.f, 0.f, 0.f, 0.f, 0.f, 0.f};
    for (unsigned e = start; e < end; e += 8) {
        unsigned i0 = e + eh, i1 = e + 4 + eh;
        uint2 d0 = (i0 < end) ? edata[i0] : make_uint2(0u, 0u);   // a=0 pad
        uint2 d1 = (i1 < end) ? edata[i1] : make_uint2(0u, 0u);
        uint4 q0 = *(const uint4*)(ftb + (size_t)d0.x * 128 + j * 8);
        uint4 q1 = *(const uint4*)(ftb + (size_t)d1.x * 128 + j * 8);
        float a0 = __uint_as_float(d0.y);
        float a1 = __uint_as_float(d1.y);
        const unsigned* w0 = (const unsigned*)&q0;
        const unsigned* w1 = (const unsigned*)&q1;
        #pragma unroll
        for (int p = 0; p < 4; ++p) {
            acc[2 * p]     += a0 * __uint_as_float(w0[p] << 16);
            acc[2 * p + 1] += a0 * __uint_as_float(w0[p] & 0xFFFF0000u);
            acc[2 * p]     += a1 * __uint_as_float(w1[p] << 16);
            acc[2 * p + 1] += a1 * __uint_as_float(w1[p] & 0xFFFF0000u);
        }
    }
    #pragma unroll
    for (int p = 0; p < 8; ++p) {
        acc[p] += __shfl_xor(acc[p], 16, 64);
        acc[p] += __shfl_xor(acc[p], 32, 64);
    }
    if (eh == 0) {
        float4* op = (float4*)(out + (size_t)d * 128 + j * 8);
        op[0] = make_float4(acc[0], acc[1], acc[2], acc[3]);
        op[1] = make_float4(acc[4], acc[5], acc[6], acc[7]);
    }
}

static inline size_t align256(size_t x) { return (x + 255) & ~(size_t)255; }

extern "C" void kernel_launch(void* const* d_in, const int* in_sizes, int n_in,
                              void* d_out, int out_size, void* d_ws, size_t ws_size,
                              hipStream_t stream) {
    const float* inputs = (const float*)d_in[0];
    const int*   src    = (const int*)d_in[1];
    const int*   dst    = (const int*)d_in[2];
    const float* fc_w   = (const float*)d_in[3];
    const float* attn_l = (const float*)d_in[4];
    const float* attn_r = (const float*)d_in[5];
    float* out = (float*)d_out;

    const int N = in_sizes[0] / 128;
    const int E = in_sizes[1];
    const int nbucket = (N + BSIZE - 1) / BSIZE;       // 391
    const int M = nbucket * NBLK;                      // 200192
    const int NB1 = (M + 1023) / 1024;                 // scan1 blocks (<=1024)
    const int slice = (E + NBLK - 1) / NBLK;
    const int GB = (N + 63) / 64;                      // gemm blocks

    char* w = (char*)d_ws;
    unsigned short* ftb = (unsigned short*)w;  w += align256((size_t)N * 128 * 2);
    float*    s_l      = (float*)w;     w += align256((size_t)N * 4);
    float*    s_r      = (float*)w;     w += align256((size_t)N * 4);
    unsigned* bh       = (unsigned*)w;  w += align256((size_t)M * 4);
    unsigned* S        = (unsigned*)w;  w += align256((size_t)M * 4);
    unsigned* partials = (unsigned*)w;  w += align256(1024 * 4);
    unsigned* offsets  = (unsigned*)w;  w += align256((size_t)N * 4);
    u16x8*    Wswz     = (u16x8*)w;     w += align256(2048 * 16);
    uint2*    staged   = (uint2*)w;     w += align256((size_t)E * 8);  // final edata

    prep_kernel<<<8, 256, 0, stream>>>(fc_w, Wswz);
    front_kernel<<<GB + NBLK, 256, 0, stream>>>(inputs, Wswz, attn_l, attn_r,
                                                ftb, s_l, s_r, N, GB,
                                                dst, bh, E, nbucket, slice);
    scan1_kernel<<<NB1, 256, 0, stream>>>(bh, S, partials, M);
    scan2_kernel<<<1, 256, 0, stream>>>(partials, NB1);
    bscatter_kernel<<<NBLK, 256, 0, stream>>>(src, dst, s_l, s_r, S, partials,
                                              staged, E, nbucket, slice);
    bsort_kernel<<<nbucket, 256, 0, stream>>>(staged, S, partials, offsets,
                                              N, E, nbucket);
    aggregate_kernel<<<(N + 3) / 4, 256, 0, stream>>>(staged, offsets, ftb, out, N);
}